// Round 27
// baseline (1162.197 us; speedup 1.0000x reference)
//
#include <hip/hip_runtime.h>
#include <hip/hip_bf16.h>
#include <stdint.h>

typedef __attribute__((ext_vector_type(4))) float f32x4;
typedef __attribute__((ext_vector_type(8))) short s16x8;
typedef __attribute__((ext_vector_type(4))) short s16x4;
typedef __attribute__((ext_vector_type(8))) _Float16 f16x8;

__device__ __forceinline__ float bf2f(unsigned short u){
  union { unsigned int i; float f; } v; v.i = ((unsigned int)u) << 16; return v.f;
}
__device__ __forceinline__ unsigned short f2bf(float f){
  union { float f; unsigned int i; } v; v.f = f;
  unsigned int r = v.i + 0x7fffu + ((v.i >> 16) & 1u);
  return (unsigned short)(r >> 16);
}
__device__ __forceinline__ unsigned short f2h(float f){
  union { _Float16 h; unsigned short u; } v; v.h = (_Float16)f; return v.u;
}
__device__ __forceinline__ void gload_lds16(const void* g, void* l){
  __builtin_amdgcn_global_load_lds(
      (const __attribute__((address_space(1))) void*)g,
      (__attribute__((address_space(3))) void*)l, 16, 0, 0);
}

// XCD-aware 1D-grid decode. id = xcd + 8*(n0i*mtiles + my)   (BN=128)
__device__ __forceinline__ void swz_decode(int id, int mtiles, int& m0, int& n0){
  const int xcd = id & 7;
  const int r = id >> 3;
  m0 = (r % mtiles) * 128;
  n0 = ((r / mtiles)*8 + xcd) * 128;
}

// ---------------- GEMM (bf16 in, f32 acc) -------------------------------------
// MODE 2: C f32 [M][N]   (used for proj only)
template<int MODE>
__global__ __launch_bounds__(256, 2)
void k_gemm(const unsigned short* __restrict__ A, const unsigned short* __restrict__ Bt,
            void* __restrict__ Cp, int M, int N, int K, int ldb){
  __shared__ unsigned short sm[16384];
  const int tid = threadIdx.x;
  const int lane = tid & 63;
  const int wid = tid >> 6;
  int m0, n0;
  swz_decode(blockIdx.x, M >> 7, m0, n0);
  const int wm = wid & 1;
  const int wn = wid >> 1;

  f32x4 acc[4][4];
  #pragma unroll
  for (int i = 0; i < 4; ++i)
    #pragma unroll
    for (int j = 0; j < 4; ++j)
      acc[i][j] = (f32x4){0.f, 0.f, 0.f, 0.f};

  const unsigned short* ga[4];
  const unsigned short* gb[4];
  unsigned short* la[4];
  unsigned short* lb[4];
  #pragma unroll
  for (int i = 0; i < 4; ++i){
    const int row = (wid*4 + i)*8 + (lane >> 3);
    const int slot = (lane & 7) ^ (row & 7);
    ga[i] = A  + (size_t)(m0 + row)*K   + slot*8;
    gb[i] = Bt + (size_t)(n0 + row)*ldb + slot*8;
    la[i] = &sm[(wid*4 + i)*512];
    lb[i] = &sm[8192 + (wid*4 + i)*512];
  }

  const int nkt = K >> 6;
  for (int kt = 0; kt < nkt; ++kt){
    if (kt) __syncthreads();
    #pragma unroll
    for (int i = 0; i < 4; ++i){
      gload_lds16(ga[i] + kt*64, la[i]);
      gload_lds16(gb[i] + kt*64, lb[i]);
    }
    __syncthreads();
    #pragma unroll
    for (int kk = 0; kk < 2; ++kk){
      s16x8 af[4], bfv[4];
      #pragma unroll
      for (int im = 0; im < 4; ++im){
        const int row = wm*64 + im*16 + (lane & 15);
        const int s = ((kk*4) | (lane >> 4)) ^ (row & 7);
        af[im] = *(const s16x8*)((const char*)sm + row*128 + s*16);
      }
      #pragma unroll
      for (int in = 0; in < 4; ++in){
        const int row = wn*64 + in*16 + (lane & 15);
        const int s = ((kk*4) | (lane >> 4)) ^ (row & 7);
        bfv[in] = *(const s16x8*)((const char*)sm + 16384 + row*128 + s*16);
      }
      #pragma unroll
      for (int im = 0; im < 4; ++im)
        #pragma unroll
        for (int in = 0; in < 4; ++in)
          acc[im][in] = __builtin_amdgcn_mfma_f32_16x16x32_bf16(af[im], bfv[in], acc[im][in], 0, 0, 0);
    }
  }

  float* C = (float*)Cp;
  #pragma unroll
  for (int im = 0; im < 4; ++im){
    const int m = m0 + wm*64 + im*16 + (lane >> 4)*4;
    #pragma unroll
    for (int in = 0; in < 4; ++in){
      const int n = n0 + wn*64 + in*16 + (lane & 15);
      #pragma unroll
      for (int r = 0; r < 4; ++r)
        C[(size_t)(m + r)*N + n] = acc[im][in][r];
    }
  }
}

// ---- qkv GEMM (bf16): 96x256 tile, K=1152, blocked f32 out [M/16][16384][16]
// grid = 12*64 = 768 (exactly 3 blocks/CU). decode m0=(rr%12)*96, n0=((rr/12)*8+xcd)*256
__global__ __launch_bounds__(256, 3)
void k_gemm4w(const unsigned short* __restrict__ A, const unsigned short* __restrict__ Bt,
              float* __restrict__ C){
  __shared__ unsigned short sm[22528];   // A 12KB @0, B 32KB @6144(shorts)
  const int tid = threadIdx.x;
  const int lane = tid & 63;
  const int wid = tid >> 6;
  const int xcd = blockIdx.x & 7;
  const int rr = blockIdx.x >> 3;
  const int m0 = (rr % 12) * 96;
  const int n0 = ((rr/12)*8 + xcd) * 256;
  const int wm = wid & 1;
  const int wn = wid >> 1;

  f32x4 acc[3][8];
  #pragma unroll
  for (int i = 0; i < 3; ++i)
    #pragma unroll
    for (int j = 0; j < 8; ++j)
      acc[i][j] = (f32x4){0.f, 0.f, 0.f, 0.f};

  const unsigned short* ga[3];
  unsigned short* la[3];
  const unsigned short* gb[8];
  unsigned short* lb[8];
  #pragma unroll
  for (int i = 0; i < 3; ++i){
    const int row = (wid*3 + i)*8 + (lane >> 3);
    const int slot = (lane & 7) ^ (row & 7);
    ga[i] = A + (size_t)(m0 + row)*1152 + slot*8;
    la[i] = &sm[(wid*3 + i)*512];
  }
  #pragma unroll
  for (int i = 0; i < 8; ++i){
    const int row = (wid*8 + i)*8 + (lane >> 3);
    const int slot = (lane & 7) ^ (row & 7);
    gb[i] = Bt + (size_t)(n0 + row)*1152 + slot*8;
    lb[i] = &sm[6144 + (wid*8 + i)*512];
  }

  for (int kt = 0; kt < 18; ++kt){
    if (kt) __syncthreads();
    #pragma unroll
    for (int i = 0; i < 3; ++i)
      gload_lds16(ga[i] + kt*64, la[i]);
    #pragma unroll
    for (int i = 0; i < 8; ++i)
      gload_lds16(gb[i] + kt*64, lb[i]);
    __syncthreads();
    #pragma unroll
    for (int kk = 0; kk < 2; ++kk){
      s16x8 af[3], bfv[8];
      #pragma unroll
      for (int im = 0; im < 3; ++im){
        const int row = wm*48 + im*16 + (lane & 15);
        const int s = ((kk*4) | (lane >> 4)) ^ (row & 7);
        af[im] = *(const s16x8*)((const char*)sm + row*128 + s*16);
      }
      #pragma unroll
      for (int in = 0; in < 8; ++in){
        const int row = wn*128 + in*16 + (lane & 15);
        const int s = ((kk*4) | (lane >> 4)) ^ (row & 7);
        bfv[in] = *(const s16x8*)((const char*)sm + 12288 + row*128 + s*16);
      }
      #pragma unroll
      for (int im = 0; im < 3; ++im)
        #pragma unroll
        for (int in = 0; in < 8; ++in)
          acc[im][in] = __builtin_amdgcn_mfma_f32_16x16x32_bf16(af[im], bfv[in], acc[im][in], 0, 0, 0);
    }
  }

  // blocked epilogue, 4 passes of 64 n-rows, 96 m-cols (t<24)
  float* ep = (float*)sm;   // [64][128] f32 (96 used, padded)
  for (int p = 0; p < 4; ++p){
    __syncthreads();
    if (wn == (p >> 1)){
      #pragma unroll
      for (int in2 = 0; in2 < 4; ++in2){
        const int n2 = in2*16 + (lane & 15);
        const int e = (n2 & 7) << 2;
        #pragma unroll
        for (int im = 0; im < 3; ++im){
          const int t = (wm*48 + im*16 + (lane >> 4)*4) >> 2;
          *(f32x4*)(&ep[n2*128 + ((t ^ e) << 2)]) = acc[im][(p & 1)*4 + in2];
        }
      }
    }
    __syncthreads();
    #pragma unroll
    for (int j = 0; j < 6; ++j){
      const int cidx = tid + j*256;
      const int n2 = cidx / 24, t = cidx % 24;
      const int e = (n2 & 7) << 2;
      const f32x4 v = *(const f32x4*)(&ep[n2*128 + ((t ^ e) << 2)]);
      const int cb = (m0 >> 4) + (t >> 2);
      const int off = (t & 3)*4;
      float* dst = C + ((size_t)cb*16384 + (n0 + p*64 + n2))*16 + off;
      *(f32x4*)dst = v;
    }
  }
}

// ------- fused pconv GEMM (fp16): 96x256 tile, qkv in one K=3456 pass --------
// B (dwT2) is PX-MAJOR [cpx][3456] fp16. grid = 12*(cpx/256)
__global__ __launch_bounds__(256, 3)
void k_gemm_f9(const unsigned short* __restrict__ Wp16, const unsigned short* __restrict__ Bt,
               float* __restrict__ qkT, unsigned short* __restrict__ vT, int startPx, int cpx){
  __shared__ unsigned short sm[22528];   // A 12KB @0, B 32KB @6144(shorts)
  const int tid = threadIdx.x;
  const int lane = tid & 63;
  const int wid = tid >> 6;
  const int xcd = blockIdx.x & 7;
  const int rr = blockIdx.x >> 3;
  const int m0 = (rr % 12) * 96;
  const int n0 = ((rr/12)*8 + xcd) * 256;
  const bool isV = (m0 >= 768);
  const int wm = wid & 1;
  const int wn = wid >> 1;

  f32x4 acc[3][8];
  #pragma unroll
  for (int i = 0; i < 3; ++i)
    #pragma unroll
    for (int j = 0; j < 8; ++j)
      acc[i][j] = (f32x4){0.f, 0.f, 0.f, 0.f};

  const unsigned short* ga[3];
  unsigned short* la[3];
  const unsigned short* gb[8];
  unsigned short* lb[8];
  #pragma unroll
  for (int i = 0; i < 3; ++i){
    const int row = (wid*3 + i)*8 + (lane >> 3);
    const int slot = (lane & 7) ^ (row & 7);
    ga[i] = Wp16 + (size_t)(m0 + row)*3456 + slot*8;
    la[i] = &sm[(wid*3 + i)*512];
  }
  #pragma unroll
  for (int i = 0; i < 8; ++i){
    const int row = (wid*8 + i)*8 + (lane >> 3);
    const int slot = (lane & 7) ^ (row & 7);
    gb[i] = Bt + (size_t)(n0 + row)*3456 + slot*8;
    lb[i] = &sm[6144 + (wid*8 + i)*512];
  }

  for (int kt = 0; kt < 54; ++kt){
    if (kt) __syncthreads();
    #pragma unroll
    for (int i = 0; i < 3; ++i)
      gload_lds16(ga[i] + kt*64, la[i]);
    #pragma unroll
    for (int i = 0; i < 8; ++i)
      gload_lds16(gb[i] + kt*64, lb[i]);
    __syncthreads();
    #pragma unroll
    for (int kk = 0; kk < 2; ++kk){
      f16x8 af[3], bfv[8];
      #pragma unroll
      for (int im = 0; im < 3; ++im){
        const int row = wm*48 + im*16 + (lane & 15);
        const int s = ((kk*4) | (lane >> 4)) ^ (row & 7);
        af[im] = *(const f16x8*)((const char*)sm + row*128 + s*16);
      }
      #pragma unroll
      for (int in = 0; in < 8; ++in){
        const int row = wn*128 + in*16 + (lane & 15);
        const int s = ((kk*4) | (lane >> 4)) ^ (row & 7);
        bfv[in] = *(const f16x8*)((const char*)sm + 12288 + row*128 + s*16);
      }
      #pragma unroll
      for (int im = 0; im < 3; ++im)
        #pragma unroll
        for (int in = 0; in < 8; ++in)
          acc[im][in] = __builtin_amdgcn_mfma_f32_16x16x32_f16(af[im], bfv[in], acc[im][in], 0, 0, 0);
    }
  }

  // epilogue: 4 passes of 64 n-rows, 96 m-cols
  float* ep = (float*)sm;   // [64][128] f32 (96 used, padded)
  for (int p = 0; p < 4; ++p){
    __syncthreads();
    if (wn == (p >> 1)){
      #pragma unroll
      for (int in2 = 0; in2 < 4; ++in2){
        const int n2 = in2*16 + (lane & 15);
        const int e = (n2 & 7) << 2;
        #pragma unroll
        for (int im = 0; im < 3; ++im){
          const int t = (wm*48 + im*16 + (lane >> 4)*4) >> 2;
          *(f32x4*)(&ep[n2*128 + ((t ^ e) << 2)]) = acc[im][(p & 1)*4 + in2];
        }
      }
    }
    __syncthreads();
    if (!isV){
      #pragma unroll
      for (int j = 0; j < 6; ++j){
        const int cidx = tid + j*256;
        const int n2 = cidx / 24, t = cidx % 24;
        const int e = (n2 & 7) << 2;
        const f32x4 v = *(const f32x4*)(&ep[n2*128 + ((t ^ e) << 2)]);
        *(f32x4*)(qkT + (size_t)(n0 + p*64 + n2)*768 + m0 + t*4) = v;
      }
    } else {
      #pragma unroll
      for (int j = 0; j < 3; ++j){
        const int cidx = tid + j*256;
        const int n2 = cidx / 12, u2 = cidx % 12;
        const int e = (n2 & 7) << 2;
        const f32x4 lo = *(const f32x4*)(&ep[n2*128 + (((2*u2    ) ^ e) << 2)]);
        const f32x4 hi = *(const f32x4*)(&ep[n2*128 + (((2*u2 + 1) ^ e) << 2)]);
        s16x8 o;
        #pragma unroll
        for (int q = 0; q < 4; ++q){ o[q] = (short)f2bf(lo[q]); o[4 + q] = (short)f2bf(hi[q]); }
        *(s16x8*)(vT + (size_t)(startPx + n0 + p*64 + n2)*384 + (m0 - 768) + u2*8) = o;
      }
    }
  }
}

// ------------- x [C][P] f32 -> xT2 [P][1152] bf16: [xh | xl | xh] -------------
__global__ __launch_bounds__(256)
void k_transpose_xhl(const float* __restrict__ x, unsigned short* __restrict__ xT2){
  __shared__ float lds[64*65];
  const int tid = threadIdx.x;
  const int px0 = blockIdx.x*64;
  const int c0 = blockIdx.y*64;
  #pragma unroll
  for (int it = 0; it < 4; ++it){
    const int idx = tid + it*256;
    const int cl = idx >> 4, col = idx & 15;
    const f32x4 v = *(const f32x4*)(x + (size_t)(c0 + cl)*16384 + px0 + col*4);
    float* d = &lds[cl*65 + col*4];
    d[0] = v[0]; d[1] = v[1]; d[2] = v[2]; d[3] = v[3];
  }
  __syncthreads();
  #pragma unroll
  for (int it = 0; it < 2; ++it){
    const int idx = tid + it*256;
    const int pl = idx >> 3, cg = idx & 7;
    s16x8 h, l;
    #pragma unroll
    for (int j = 0; j < 8; ++j){
      const float v = lds[(cg*8 + j)*65 + pl];
      const unsigned short hb = f2bf(v);
      h[j] = (short)hb;
      l[j] = (short)f2bf(v - bf2f(hb));
    }
    unsigned short* o = xT2 + (size_t)(px0 + pl)*1152 + c0 + cg*8;
    *(s16x8*)(o)       = h;
    *(s16x8*)(o + 384) = l;
    *(s16x8*)(o + 768) = h;
  }
}

// ------------- fused depthwise 3/5/7 on blocked f32 base2[72][16384][16] ------
// 512 threads/block, 8 output rows/block (4 rows per thread); out PX-MAJOR fp16
__global__ __launch_bounds__(512, 1)
void k_dwconv(const float* __restrict__ base2,
              const float* __restrict__ w3, const float* __restrict__ w5,
              const float* __restrict__ w7, unsigned short* __restrict__ dwT2,
              int y_base_rows, int start_px, int cpx){
  __shared__ float tile[14*72*16];            // 64.5 KB
  __shared__ float wl[16*83];                 // 5.3 KB
  const int tid = threadIdx.x;
  const int cb = blockIdx.x;
  const int c0 = cb*16;
  const int y0 = y_base_rows + blockIdx.y*8;
  const int x0 = blockIdx.z*64;

  for (int u = tid; u < 16*83; u += 512){
    float wv;
    if (u < 144){ const int tap = u >> 4, cl = u & 15; wv = w3[(c0 + cl)*9 + tap]; }
    else if (u < 544){ const int v2 = u - 144; const int tap = v2/16, cl = v2%16; wv = w5[(c0 + cl)*25 + tap]; }
    else { const int v2 = u - 544; const int tap = v2/16, cl = v2%16; wv = w7[(c0 + cl)*49 + tap]; }
    wl[u] = wv;
  }
  const float* bb = base2 + (size_t)cb*16384*16;
  for (int u = tid; u < 4032; u += 512){
    const int r = u / 288;
    const int rem = u % 288;
    const int xig = rem >> 2;
    const int cq = rem & 3;
    const int y = y0 + r - 3;
    const int xg = x0 + xig - 3;
    f32x4 v = {0.f,0.f,0.f,0.f};
    if ((unsigned)y < 128u && (unsigned)xg < 128u)
      v = *(const f32x4*)(bb + (size_t)(y*128 + xg)*16 + cq*4);
    *(f32x4*)(&tile[(r*72 + xig)*16 + cq*4]) = v;
  }
  __syncthreads();

  const int cq = tid & 3;
  const int xl = (tid >> 2) & 63;
  const int rh = tid >> 8;          // 0..1: row-group of 4
  const float* w3t = wl;
  const float* w5t = wl + 144;
  const float* w7t = wl + 544;

  f32x4 a3[4], a5[4], a7[4];
  #pragma unroll
  for (int r = 0; r < 4; ++r){
    a3[r] = (f32x4){0.f,0.f,0.f,0.f};
    a5[r] = (f32x4){0.f,0.f,0.f,0.f};
    a7[r] = (f32x4){0.f,0.f,0.f,0.f};
  }
  #pragma unroll
  for (int dy = 0; dy < 7; ++dy){
    #pragma unroll
    for (int dx = 0; dx < 7; ++dx){
      const f32x4 w7v = *(const f32x4*)(&w7t[(dy*7 + dx)*16 + cq*4]);
      const bool in5 = (dy >= 1 && dy <= 5 && dx >= 1 && dx <= 5);
      const bool in3 = (dy >= 2 && dy <= 4 && dx >= 2 && dx <= 4);
      f32x4 w5v = {0.f,0.f,0.f,0.f}, w3v = {0.f,0.f,0.f,0.f};
      if (in5) w5v = *(const f32x4*)(&w5t[((dy - 1)*5 + (dx - 1))*16 + cq*4]);
      if (in3) w3v = *(const f32x4*)(&w3t[((dy - 2)*3 + (dx - 2))*16 + cq*4]);
      #pragma unroll
      for (int r = 0; r < 4; ++r){
        const f32x4 f = *(const f32x4*)(&tile[((rh*4 + r + dy)*72 + (xl + dx))*16 + cq*4]);
        a7[r] += f*w7v;
        if (in5) a5[r] += f*w5v;
        if (in3) a3[r] += f*w3v;
      }
    }
  }

  #pragma unroll
  for (int r = 0; r < 4; ++r){
    const int p = (y0 + rh*4 + r)*128 + x0 + xl;
    unsigned short* ob = dwT2 + (size_t)(p - start_px)*3456 + cb*48 + cq*4;
    s16x4 h3, h5, h7;
    #pragma unroll
    for (int j = 0; j < 4; ++j){
      h3[j] = (short)f2h(a3[r][j]);
      h5[j] = (short)f2h(a5[r][j]);
      h7[j] = (short)f2h(a7[r][j]);
    }
    *(s16x4*)(ob)      = h3;
    *(s16x4*)(ob + 16) = h5;
    *(s16x4*)(ob + 32) = h7;
  }
}

// ---- attention partials v2: one block = 64-px slot, ALL 8 heads -------------
// stages 16px x 768 f32 once; qkT read exactly once. part [8][256][2400]
__global__ __launch_bounds__(256, 2)
void k_attn_partial2(const float* __restrict__ qkT, float* __restrict__ part, int slotBase){
  __shared__ float qk[16*772];    // 49.4 KB, padded rows
  const int tid = threadIdx.x;
  const int slot = blockIdx.x;
  const int c0 = tid & 15;
  const int d0 = tid >> 4;

  float acc[8][3][3];
  #pragma unroll
  for (int h = 0; h < 8; ++h)
    #pragma unroll
    for (int i = 0; i < 3; ++i)
      #pragma unroll
      for (int j = 0; j < 3; ++j)
        acc[h][i][j] = 0.f;
  float ssq0 = 0.f, ssq1 = 0.f, ssq2 = 0.f;
  const int ch = tid*3;

  for (int sub = 0; sub < 4; ++sub){
    __syncthreads();
    const int pb = slot*64 + sub*16;
    #pragma unroll
    for (int it = 0; it < 12; ++it){
      const int idx = tid + it*256;
      const int px = idx / 192, s = idx % 192;
      *(f32x4*)(&qk[px*772 + s*4]) = *(const f32x4*)(qkT + (size_t)(pb + px)*768 + s*4);
    }
    __syncthreads();
    for (int px = 0; px < 16; ++px){
      const float* row = &qk[px*772];
      #pragma unroll
      for (int h = 0; h < 8; ++h){
        const float q0 = row[h*48 + c0*3 + 0];
        const float q1 = row[h*48 + c0*3 + 1];
        const float q2 = row[h*48 + c0*3 + 2];
        const float k0 = row[384 + h*48 + d0*3 + 0];
        const float k1 = row[384 + h*48 + d0*3 + 1];
        const float k2 = row[384 + h*48 + d0*3 + 2];
        acc[h][0][0] += q0*k0; acc[h][0][1] += q0*k1; acc[h][0][2] += q0*k2;
        acc[h][1][0] += q1*k0; acc[h][1][1] += q1*k1; acc[h][1][2] += q1*k2;
        acc[h][2][0] += q2*k0; acc[h][2][1] += q2*k1; acc[h][2][2] += q2*k2;
      }
      ssq0 += row[ch]*row[ch];
      ssq1 += row[ch + 1]*row[ch + 1];
      ssq2 += row[ch + 2]*row[ch + 2];
    }
  }

  #pragma unroll
  for (int h = 0; h < 8; ++h){
    float* pp = part + ((size_t)h*256 + slotBase + slot)*2400;
    #pragma unroll
    for (int i = 0; i < 3; ++i)
      #pragma unroll
      for (int j = 0; j < 3; ++j)
        pp[(c0*3 + i)*48 + d0*3 + j] = acc[h][i][j];
  }
  {
    const int hh = (ch < 384) ? (ch / 48) : ((ch - 384) / 48);
    const int cc = (ch < 384) ? (ch % 48) : (48 + ((ch - 384) % 48));
    float* pp = part + ((size_t)hh*256 + slotBase + slot)*2400 + 2304 + cc;
    pp[0] = ssq0; pp[1] = ssq1; pp[2] = ssq2;
  }
}

// ------- reduce 256 partials, l2-norm, temperature, fused 3x topk-softmax ----
__global__ __launch_bounds__(256)
void k_attn_combine(const float* __restrict__ part, const float* __restrict__ temp,
                    const float* __restrict__ scales, float* __restrict__ Acomb){
  __shared__ float att[288];
  const int tid = threadIdx.x;
  const int rg = blockIdx.x;
  const int h = blockIdx.y;
  const int r0 = rg*4;
  for (int u = tid; u < 288; u += 256){
    const int off = (u < 192) ? ((r0 + u/48)*48 + (u % 48)) : (2304 + (u - 192));
    float s = 0.f;
    const float* pb = part + (size_t)h*256*2400 + off;
    for (int c2 = 0; c2 < 256; ++c2) s += pb[c2*2400];
    att[u] = s;
  }
  __syncthreads();
  const int w = tid >> 6;
  const int lane = tid & 63;
  const int c = r0 + w;
  const int d = lane;
  const float tmp = temp[h];
  float v;
  if (d < 48){
    const float nq = fmaxf(sqrtf(att[192 + c]), 1e-12f);
    const float nk = fmaxf(sqrtf(att[240 + d]), 1e-12f);
    v = att[w*48 + d] / (nq*nk) * tmp;
  } else v = -3.0e38f;
  float m = v;
  #pragma unroll
  for (int s = 32; s; s >>= 1) m = fmaxf(m, __shfl_xor(m, s, 64));
  int rk = 0;
  for (int l = 0; l < 48; ++l){
    const float vl = __shfl(v, l, 64);
    rk += ((vl > v) || (vl == v && l < d)) ? 1 : 0;
  }
  const float e = (d < 48) ? expf(v - m) : 0.f;
  float e0 = (rk < 24) ? e : 0.f;
  float e1 = (rk < 32) ? e : 0.f;
  float e2 = (rk < 36) ? e : 0.f;
  #pragma unroll
  for (int s = 32; s; s >>= 1){
    e0 += __shfl_xor(e0, s, 64);
    e1 += __shfl_xor(e1, s, 64);
    e2 += __shfl_xor(e2, s, 64);
  }
  const float wgt = e*(((rk < 24) ? scales[0]/e0 : 0.f)
                     + ((rk < 32) ? scales[1]/e1 : 0.f)
                     + ((rk < 36) ? scales[2]/e2 : 0.f));
  if (d < 48) Acomb[((size_t)h*48 + c)*48 + d] = wgt;
}

// ------------- out[p][h*48+c] = sum_d Acomb[h][c][d] * v[p][d]  (bf16 out) ---
__global__ __launch_bounds__(256, 2)
void k_av(const unsigned short* __restrict__ vT, const float* __restrict__ Acomb,
          unsigned short* __restrict__ outT){
  __shared__ float As[48*49];
  __shared__ float vs[64*48];
  const int tid = threadIdx.x;
  const int pc = blockIdx.x;
  const int h = blockIdx.y;
  for (int u = tid; u < 2304; u += 256)
    As[(u/48)*49 + (u%48)] = Acomb[(size_t)h*2304 + u];
  const int q = tid & 3;
  const int pl = tid >> 2;
  for (int st = 0; st < 4; ++st){
    __syncthreads();
    const int pb = pc*256 + st*64;
    #pragma unroll
    for (int it = 0; it < 2; ++it){
      const int u = tid + it*256;
      if (u < 384){
        const int p = u / 6, sg = u % 6;
        const s16x8 v8 = *(const s16x8*)(vT + (size_t)(pb + p)*384 + h*48 + sg*8);
        float* d = &vs[p*48 + sg*8];
        #pragma unroll
        for (int j = 0; j < 8; ++j) d[j] = bf2f((unsigned short)v8[j]);
      }
    }
    __syncthreads();
    float a[12];
    #pragma unroll
    for (int i = 0; i < 12; ++i) a[i] = 0.f;
    for (int d = 0; d < 48; ++d){
      const float vv = vs[pl*48 + d];
      #pragma unroll
      for (int i = 0; i < 12; ++i) a[i] += As[(q*12 + i)*49 + d]*vv;
    }
    unsigned short* ob = outT + (size_t)(pb + pl)*384 + h*48 + q*12;
    #pragma unroll
    for (int g = 0; g < 3; ++g){
      s16x4 o;
      #pragma unroll
      for (int j = 0; j < 4; ++j) o[j] = (short)f2bf(a[g*4 + j]);
      *(s16x4*)(ob + g*4) = o;
    }
  }
}

// ------------- weight prep ----------------------------------------------------
__global__ __launch_bounds__(256)
void k_f32_to_bf16(const float* __restrict__ in, unsigned short* __restrict__ out, int n4){
  const int i = blockIdx.x*256 + threadIdx.x;
  if (i < n4){
    const f32x4 v = *(const f32x4*)(in + (size_t)i*4);
    s16x4 o;
    #pragma unroll
    for (int j = 0; j < 4; ++j) o[j] = (short)f2bf(v[j]);
    *(s16x4*)(out + (size_t)i*4) = o;
  }
}
__global__ __launch_bounds__(256)
void k_prep_wqkv(const float* __restrict__ w, unsigned short* __restrict__ A){
  const int i = blockIdx.x*256 + threadIdx.x;
  const int o = i / 384, c = i % 384;
  const float v = w[i];
  const unsigned short hi = f2bf(v);
  const unsigned short lo = f2bf(v - bf2f(hi));
  unsigned short* r = A + (size_t)o*1152;
  r[c] = hi; r[384 + c] = hi; r[768 + c] = lo;
}
// pconv weights -> single fp16 plane, K-permuted (k' = cbl*48 + br*16 + cl)
__global__ __launch_bounds__(256)
void k_prep_wp16(const float* __restrict__ w, unsigned short* __restrict__ wp16){
  const int i = blockIdx.x*256 + threadIdx.x;   // 1152*3456 threads
  const int o = i / 3456, k3 = i % 3456;
  const int cbl = k3 / 48, r2 = k3 % 48, br = r2 / 16, cl = r2 % 16;
  wp16[(size_t)o*3456 + k3] = f2h(w[(size_t)o*3456 + br*1152 + cbl*16 + cl]);
}

extern "C" void kernel_launch(void* const* d_in, const int* in_sizes, int n_in,
                              void* d_out, int out_size, void* d_ws, size_t ws_size,
                              hipStream_t stream){
  const float* x         = (const float*)d_in[0];
  const float* w_qkv     = (const float*)d_in[1];
  const float* w_dw3     = (const float*)d_in[2];
  const float* w_dw5     = (const float*)d_in[3];
  const float* w_dw7     = (const float*)d_in[4];
  const float* w_pconv   = (const float*)d_in[5];
  const float* w_proj    = (const float*)d_in[6];
  const float* temperature = (const float*)d_in[7];
  const float* attn_scales = (const float*)d_in[8];
  float* out = (float*)d_out;
  char* ws = (char*)d_ws;
  const size_t MiB = (size_t)1 << 20;

  // fixed region (0..24 MiB)
  unsigned short* Aqkv  = (unsigned short*)(ws);               // 2.53 MiB
  unsigned short* Wp16  = (unsigned short*)(ws + 3*MiB);       // 7.6 MiB
  unsigned short* Wproj = (unsigned short*)(ws + 11*MiB);      // 0.28 MiB
  unsigned short* vT    = (unsigned short*)(ws + 12*MiB);      // 12 MiB
  // tail (last 33 MiB): part [8][256][2400] f32 (18.75) + Acomb + outT (12)
  char* tailp = ws + (ws_size - 33*MiB);
  float*          part  = (float*)tailp;
  float*          Acomb = (float*)(tailp + 20*MiB);
  unsigned short* outT  = (unsigned short*)(tailp + 21*MiB);

  float*          base2;
  float*          qkTc;
  unsigned short* dwT2;
  unsigned short* xT2;
  int units;
  if (ws_size >= 237*MiB){
    // SINGLE-CHUNK: base2@24 (dead after dwconv) aliased by qkTc; dwT2@96 (108 MiB)
    base2 = (float*)(ws + 24*MiB);
    qkTc  = (float*)(ws + 24*MiB);             // aliases base2 (base2 dead when f9 runs)
    dwT2  = (unsigned short*)(ws + 96*MiB);    // [16384][3456] fp16 = 108 MiB
    xT2   = (unsigned short*)(ws + 96*MiB);    // aliases dwT2 (dead before dwconv)
    units = 16;
  } else {
    // CHUNKED fallback: base2@24..96, qkTc@96, dwT2 after
    base2 = (float*)(ws + 24*MiB);
    long long avail = (long long)ws_size - (long long)(96 + 33)*MiB;
    units = (int)(avail / (1024LL*768*4 + 1024LL*3456*2));
    if (units > 16) units = 16;
    units &= ~1;
    if (units < 2) units = 2;
    qkTc = (float*)(ws + 96*MiB);
    dwT2 = (unsigned short*)(ws + 96*MiB + (size_t)units*3*MiB);
    xT2  = (unsigned short*)(ws + 96*MiB);
  }

  k_prep_wqkv<<<dim3(1728), dim3(256), 0, stream>>>(w_qkv, Aqkv);
  k_prep_wp16<<<dim3(15552), dim3(256), 0, stream>>>(w_pconv, Wp16);
  k_f32_to_bf16<<<dim3(144), dim3(256), 0, stream>>>(w_proj, Wproj, 36864);

  for (int b = 0; b < 2; ++b){
    const float* xb = x + (size_t)b*384*16384;
    float* outb = out + (size_t)b*384*16384;
    k_transpose_xhl<<<dim3(256, 6), dim3(256), 0, stream>>>(xb, xT2);
    // base = Wqkv * x  (3-term hi/lo, blocked f32 out); 96x256 tile, 768 blocks
    k_gemm4w<<<dim3(768), dim3(256), 0, stream>>>(Aqkv, xT2, base2);
    for (int u0 = 0; u0 < 16; u0 += units){
      const int cu = (units < 16 - u0) ? units : (16 - u0);
      const int start = u0*1024, cpx = cu*1024;
      k_dwconv<<<dim3(72, cu, 2), dim3(512), 0, stream>>>(base2, w_dw3, w_dw5, w_dw7,
                                                          dwT2, start/128, start, cpx);
      // qkv in one fp16 GEMM (96x256 tile, 12*(cpx/256) blocks), px-major B rows
      k_gemm_f9<<<dim3((cpx/256)*12), dim3(256), 0, stream>>>(Wp16, dwT2, qkTc, vT, start, cpx);
      // partial QK^T dots: one block per 64-px slot, all 8 heads, single read
      k_attn_partial2<<<dim3(cpx/64), dim3(256), 0, stream>>>(qkTc, part, start/64);
    }
    k_attn_combine<<<dim3(12, 8), dim3(256), 0, stream>>>(part, temperature, attn_scales, Acomb);
    k_av<<<dim3(64, 8), dim3(256), 0, stream>>>(vT, Acomb, outT);
    k_gemm<2><<<dim3(128*3), dim3(256), 0, stream>>>(Wproj, outT, outb, 384, 16384, 384, 384);
  }
  (void)in_sizes; (void)n_in; (void)out_size; (void)ws_size;
}

// Round 28
// 865.033 us; speedup vs baseline: 1.3435x; 1.3435x over previous
//
#include <hip/hip_runtime.h>
#include <hip/hip_bf16.h>
#include <stdint.h>

typedef __attribute__((ext_vector_type(4))) float f32x4;
typedef __attribute__((ext_vector_type(8))) short s16x8;
typedef __attribute__((ext_vector_type(4))) short s16x4;
typedef __attribute__((ext_vector_type(8))) _Float16 f16x8;

__device__ __forceinline__ float bf2f(unsigned short u){
  union { unsigned int i; float f; } v; v.i = ((unsigned int)u) << 16; return v.f;
}
__device__ __forceinline__ unsigned short f2bf(float f){
  union { float f; unsigned int i; } v; v.f = f;
  unsigned int r = v.i + 0x7fffu + ((v.i >> 16) & 1u);
  return (unsigned short)(r >> 16);
}
__device__ __forceinline__ unsigned short f2h(float f){
  union { _Float16 h; unsigned short u; } v; v.h = (_Float16)f; return v.u;
}
__device__ __forceinline__ void gload_lds16(const void* g, void* l){
  __builtin_amdgcn_global_load_lds(
      (const __attribute__((address_space(1))) void*)g,
      (__attribute__((address_space(3))) void*)l, 16, 0, 0);
}

// ---- proj GEMM (bf16): 96x128 tile, K=384, C f32 [384][16384] direct --------
// grid = 4*128 = 512 (exactly 2/CU). decode m0=(rr%4)*96, n0=((rr/4)*8+xcd)*128
__global__ __launch_bounds__(256, 3)
void k_gemm_proj(const unsigned short* __restrict__ A, const unsigned short* __restrict__ Bt,
                 float* __restrict__ C){
  __shared__ unsigned short sm[14336];   // A 12KB @0, B 16KB @6144(shorts)
  const int tid = threadIdx.x;
  const int lane = tid & 63;
  const int wid = tid >> 6;
  const int xcd = blockIdx.x & 7;
  const int rr = blockIdx.x >> 3;
  const int m0 = (rr % 4) * 96;
  const int n0 = ((rr/4)*8 + xcd) * 128;
  const int wm = wid & 1;
  const int wn = wid >> 1;

  f32x4 acc[3][4];
  #pragma unroll
  for (int i = 0; i < 3; ++i)
    #pragma unroll
    for (int j = 0; j < 4; ++j)
      acc[i][j] = (f32x4){0.f, 0.f, 0.f, 0.f};

  const unsigned short* ga[3];
  unsigned short* la[3];
  const unsigned short* gb[4];
  unsigned short* lb[4];
  #pragma unroll
  for (int i = 0; i < 3; ++i){
    const int row = (wid*3 + i)*8 + (lane >> 3);
    const int slot = (lane & 7) ^ (row & 7);
    ga[i] = A + (size_t)(m0 + row)*384 + slot*8;
    la[i] = &sm[(wid*3 + i)*512];
  }
  #pragma unroll
  for (int i = 0; i < 4; ++i){
    const int row = (wid*4 + i)*8 + (lane >> 3);
    const int slot = (lane & 7) ^ (row & 7);
    gb[i] = Bt + (size_t)(n0 + row)*384 + slot*8;
    lb[i] = &sm[6144 + (wid*4 + i)*512];
  }

  for (int kt = 0; kt < 6; ++kt){
    if (kt) __syncthreads();
    #pragma unroll
    for (int i = 0; i < 3; ++i)
      gload_lds16(ga[i] + kt*64, la[i]);
    #pragma unroll
    for (int i = 0; i < 4; ++i)
      gload_lds16(gb[i] + kt*64, lb[i]);
    __syncthreads();
    #pragma unroll
    for (int kk = 0; kk < 2; ++kk){
      s16x8 af[3], bfv[4];
      #pragma unroll
      for (int im = 0; im < 3; ++im){
        const int row = wm*48 + im*16 + (lane & 15);
        const int s = ((kk*4) | (lane >> 4)) ^ (row & 7);
        af[im] = *(const s16x8*)((const char*)sm + row*128 + s*16);
      }
      #pragma unroll
      for (int in = 0; in < 4; ++in){
        const int row = wn*64 + in*16 + (lane & 15);
        const int s = ((kk*4) | (lane >> 4)) ^ (row & 7);
        bfv[in] = *(const s16x8*)((const char*)sm + 12288 + row*128 + s*16);
      }
      #pragma unroll
      for (int im = 0; im < 3; ++im)
        #pragma unroll
        for (int in = 0; in < 4; ++in)
          acc[im][in] = __builtin_amdgcn_mfma_f32_16x16x32_bf16(af[im], bfv[in], acc[im][in], 0, 0, 0);
    }
  }

  #pragma unroll
  for (int im = 0; im < 3; ++im){
    const int m = m0 + wm*48 + im*16 + (lane >> 4)*4;
    #pragma unroll
    for (int in = 0; in < 4; ++in){
      const int n = n0 + wn*64 + in*16 + (lane & 15);
      #pragma unroll
      for (int r = 0; r < 4; ++r)
        C[(size_t)(m + r)*16384 + n] = acc[im][in][r];
    }
  }
}

// ---- qkv GEMM (bf16): 96x256 tile, K=1152, blocked f32 out [M/16][16384][16]
// grid = 12*64 = 768 (exactly 3 blocks/CU). decode m0=(rr%12)*96, n0=((rr/12)*8+xcd)*256
__global__ __launch_bounds__(256, 3)
void k_gemm4w(const unsigned short* __restrict__ A, const unsigned short* __restrict__ Bt,
              float* __restrict__ C){
  __shared__ unsigned short sm[22528];   // A 12KB @0, B 32KB @6144(shorts)
  const int tid = threadIdx.x;
  const int lane = tid & 63;
  const int wid = tid >> 6;
  const int xcd = blockIdx.x & 7;
  const int rr = blockIdx.x >> 3;
  const int m0 = (rr % 12) * 96;
  const int n0 = ((rr/12)*8 + xcd) * 256;
  const int wm = wid & 1;
  const int wn = wid >> 1;

  f32x4 acc[3][8];
  #pragma unroll
  for (int i = 0; i < 3; ++i)
    #pragma unroll
    for (int j = 0; j < 8; ++j)
      acc[i][j] = (f32x4){0.f, 0.f, 0.f, 0.f};

  const unsigned short* ga[3];
  unsigned short* la[3];
  const unsigned short* gb[8];
  unsigned short* lb[8];
  #pragma unroll
  for (int i = 0; i < 3; ++i){
    const int row = (wid*3 + i)*8 + (lane >> 3);
    const int slot = (lane & 7) ^ (row & 7);
    ga[i] = A + (size_t)(m0 + row)*1152 + slot*8;
    la[i] = &sm[(wid*3 + i)*512];
  }
  #pragma unroll
  for (int i = 0; i < 8; ++i){
    const int row = (wid*8 + i)*8 + (lane >> 3);
    const int slot = (lane & 7) ^ (row & 7);
    gb[i] = Bt + (size_t)(n0 + row)*1152 + slot*8;
    lb[i] = &sm[6144 + (wid*8 + i)*512];
  }

  for (int kt = 0; kt < 18; ++kt){
    if (kt) __syncthreads();
    #pragma unroll
    for (int i = 0; i < 3; ++i)
      gload_lds16(ga[i] + kt*64, la[i]);
    #pragma unroll
    for (int i = 0; i < 8; ++i)
      gload_lds16(gb[i] + kt*64, lb[i]);
    __syncthreads();
    #pragma unroll
    for (int kk = 0; kk < 2; ++kk){
      s16x8 af[3], bfv[8];
      #pragma unroll
      for (int im = 0; im < 3; ++im){
        const int row = wm*48 + im*16 + (lane & 15);
        const int s = ((kk*4) | (lane >> 4)) ^ (row & 7);
        af[im] = *(const s16x8*)((const char*)sm + row*128 + s*16);
      }
      #pragma unroll
      for (int in = 0; in < 8; ++in){
        const int row = wn*128 + in*16 + (lane & 15);
        const int s = ((kk*4) | (lane >> 4)) ^ (row & 7);
        bfv[in] = *(const s16x8*)((const char*)sm + 12288 + row*128 + s*16);
      }
      #pragma unroll
      for (int im = 0; im < 3; ++im)
        #pragma unroll
        for (int in = 0; in < 8; ++in)
          acc[im][in] = __builtin_amdgcn_mfma_f32_16x16x32_bf16(af[im], bfv[in], acc[im][in], 0, 0, 0);
    }
  }

  // blocked epilogue, 4 passes of 64 n-rows, 96 m-cols (t<24)
  float* ep = (float*)sm;   // [64][128] f32 (96 used, padded)
  for (int p = 0; p < 4; ++p){
    __syncthreads();
    if (wn == (p >> 1)){
      #pragma unroll
      for (int in2 = 0; in2 < 4; ++in2){
        const int n2 = in2*16 + (lane & 15);
        const int e = (n2 & 7) << 2;
        #pragma unroll
        for (int im = 0; im < 3; ++im){
          const int t = (wm*48 + im*16 + (lane >> 4)*4) >> 2;
          *(f32x4*)(&ep[n2*128 + ((t ^ e) << 2)]) = acc[im][(p & 1)*4 + in2];
        }
      }
    }
    __syncthreads();
    #pragma unroll
    for (int j = 0; j < 6; ++j){
      const int cidx = tid + j*256;
      const int n2 = cidx / 24, t = cidx % 24;
      const int e = (n2 & 7) << 2;
      const f32x4 v = *(const f32x4*)(&ep[n2*128 + ((t ^ e) << 2)]);
      const int cb = (m0 >> 4) + (t >> 2);
      const int off = (t & 3)*4;
      float* dst = C + ((size_t)cb*16384 + (n0 + p*64 + n2))*16 + off;
      *(f32x4*)dst = v;
    }
  }
}

// ------- fused pconv GEMM (fp16): 96x256 tile, qkv in one K=3456 pass --------
// B (dwT2) is PX-MAJOR [cpx][3456] fp16. grid = 12*(cpx/256)
__global__ __launch_bounds__(256, 3)
void k_gemm_f9(const unsigned short* __restrict__ Wp16, const unsigned short* __restrict__ Bt,
               float* __restrict__ qkT, unsigned short* __restrict__ vT, int startPx, int cpx){
  __shared__ unsigned short sm[22528];   // A 12KB @0, B 32KB @6144(shorts)
  const int tid = threadIdx.x;
  const int lane = tid & 63;
  const int wid = tid >> 6;
  const int xcd = blockIdx.x & 7;
  const int rr = blockIdx.x >> 3;
  const int m0 = (rr % 12) * 96;
  const int n0 = ((rr/12)*8 + xcd) * 256;
  const bool isV = (m0 >= 768);
  const int wm = wid & 1;
  const int wn = wid >> 1;

  f32x4 acc[3][8];
  #pragma unroll
  for (int i = 0; i < 3; ++i)
    #pragma unroll
    for (int j = 0; j < 8; ++j)
      acc[i][j] = (f32x4){0.f, 0.f, 0.f, 0.f};

  const unsigned short* ga[3];
  unsigned short* la[3];
  const unsigned short* gb[8];
  unsigned short* lb[8];
  #pragma unroll
  for (int i = 0; i < 3; ++i){
    const int row = (wid*3 + i)*8 + (lane >> 3);
    const int slot = (lane & 7) ^ (row & 7);
    ga[i] = Wp16 + (size_t)(m0 + row)*3456 + slot*8;
    la[i] = &sm[(wid*3 + i)*512];
  }
  #pragma unroll
  for (int i = 0; i < 8; ++i){
    const int row = (wid*8 + i)*8 + (lane >> 3);
    const int slot = (lane & 7) ^ (row & 7);
    gb[i] = Bt + (size_t)(n0 + row)*3456 + slot*8;
    lb[i] = &sm[6144 + (wid*8 + i)*512];
  }

  for (int kt = 0; kt < 54; ++kt){
    if (kt) __syncthreads();
    #pragma unroll
    for (int i = 0; i < 3; ++i)
      gload_lds16(ga[i] + kt*64, la[i]);
    #pragma unroll
    for (int i = 0; i < 8; ++i)
      gload_lds16(gb[i] + kt*64, lb[i]);
    __syncthreads();
    #pragma unroll
    for (int kk = 0; kk < 2; ++kk){
      f16x8 af[3], bfv[8];
      #pragma unroll
      for (int im = 0; im < 3; ++im){
        const int row = wm*48 + im*16 + (lane & 15);
        const int s = ((kk*4) | (lane >> 4)) ^ (row & 7);
        af[im] = *(const f16x8*)((const char*)sm + row*128 + s*16);
      }
      #pragma unroll
      for (int in = 0; in < 8; ++in){
        const int row = wn*128 + in*16 + (lane & 15);
        const int s = ((kk*4) | (lane >> 4)) ^ (row & 7);
        bfv[in] = *(const f16x8*)((const char*)sm + 12288 + row*128 + s*16);
      }
      #pragma unroll
      for (int im = 0; im < 3; ++im)
        #pragma unroll
        for (int in = 0; in < 8; ++in)
          acc[im][in] = __builtin_amdgcn_mfma_f32_16x16x32_f16(af[im], bfv[in], acc[im][in], 0, 0, 0);
    }
  }

  // epilogue: 4 passes of 64 n-rows, 96 m-cols
  float* ep = (float*)sm;   // [64][128] f32 (96 used, padded)
  for (int p = 0; p < 4; ++p){
    __syncthreads();
    if (wn == (p >> 1)){
      #pragma unroll
      for (int in2 = 0; in2 < 4; ++in2){
        const int n2 = in2*16 + (lane & 15);
        const int e = (n2 & 7) << 2;
        #pragma unroll
        for (int im = 0; im < 3; ++im){
          const int t = (wm*48 + im*16 + (lane >> 4)*4) >> 2;
          *(f32x4*)(&ep[n2*128 + ((t ^ e) << 2)]) = acc[im][(p & 1)*4 + in2];
        }
      }
    }
    __syncthreads();
    if (!isV){
      #pragma unroll
      for (int j = 0; j < 6; ++j){
        const int cidx = tid + j*256;
        const int n2 = cidx / 24, t = cidx % 24;
        const int e = (n2 & 7) << 2;
        const f32x4 v = *(const f32x4*)(&ep[n2*128 + ((t ^ e) << 2)]);
        *(f32x4*)(qkT + (size_t)(n0 + p*64 + n2)*768 + m0 + t*4) = v;
      }
    } else {
      #pragma unroll
      for (int j = 0; j < 3; ++j){
        const int cidx = tid + j*256;
        const int n2 = cidx / 12, u2 = cidx % 12;
        const int e = (n2 & 7) << 2;
        const f32x4 lo = *(const f32x4*)(&ep[n2*128 + (((2*u2    ) ^ e) << 2)]);
        const f32x4 hi = *(const f32x4*)(&ep[n2*128 + (((2*u2 + 1) ^ e) << 2)]);
        s16x8 o;
        #pragma unroll
        for (int q = 0; q < 4; ++q){ o[q] = (short)f2bf(lo[q]); o[4 + q] = (short)f2bf(hi[q]); }
        *(s16x8*)(vT + (size_t)(startPx + n0 + p*64 + n2)*384 + (m0 - 768) + u2*8) = o;
      }
    }
  }
}

// ------------- x [C][P] f32 -> xT2 [P][1152] bf16: [xh | xl | xh] -------------
__global__ __launch_bounds__(256)
void k_transpose_xhl(const float* __restrict__ x, unsigned short* __restrict__ xT2){
  __shared__ float lds[64*65];
  const int tid = threadIdx.x;
  const int px0 = blockIdx.x*64;
  const int c0 = blockIdx.y*64;
  #pragma unroll
  for (int it = 0; it < 4; ++it){
    const int idx = tid + it*256;
    const int cl = idx >> 4, col = idx & 15;
    const f32x4 v = *(const f32x4*)(x + (size_t)(c0 + cl)*16384 + px0 + col*4);
    float* d = &lds[cl*65 + col*4];
    d[0] = v[0]; d[1] = v[1]; d[2] = v[2]; d[3] = v[3];
  }
  __syncthreads();
  #pragma unroll
  for (int it = 0; it < 2; ++it){
    const int idx = tid + it*256;
    const int pl = idx >> 3, cg = idx & 7;
    s16x8 h, l;
    #pragma unroll
    for (int j = 0; j < 8; ++j){
      const float v = lds[(cg*8 + j)*65 + pl];
      const unsigned short hb = f2bf(v);
      h[j] = (short)hb;
      l[j] = (short)f2bf(v - bf2f(hb));
    }
    unsigned short* o = xT2 + (size_t)(px0 + pl)*1152 + c0 + cg*8;
    *(s16x8*)(o)       = h;
    *(s16x8*)(o + 384) = l;
    *(s16x8*)(o + 768) = h;
  }
}

// ------------- fused depthwise 3/5/7 on blocked f32 base2[72][16384][16] ------
// 512 threads/block (2 rows per thread); out PX-MAJOR fp16 [cpx][3456]
__global__ __launch_bounds__(512, 1)
void k_dwconv(const float* __restrict__ base2,
              const float* __restrict__ w3, const float* __restrict__ w5,
              const float* __restrict__ w7, unsigned short* __restrict__ dwT2,
              int y_base_rows, int start_px, int cpx){
  __shared__ float tile[10*72*16];            // 46.1 KB
  __shared__ float wl[16*83];                 // 5.3 KB
  const int tid = threadIdx.x;
  const int cb = blockIdx.x;
  const int c0 = cb*16;
  const int y0 = y_base_rows + blockIdx.y*4;
  const int x0 = blockIdx.z*64;

  for (int u = tid; u < 16*83; u += 512){
    float wv;
    if (u < 144){ const int tap = u >> 4, cl = u & 15; wv = w3[(c0 + cl)*9 + tap]; }
    else if (u < 544){ const int v2 = u - 144; const int tap = v2/16, cl = v2%16; wv = w5[(c0 + cl)*25 + tap]; }
    else { const int v2 = u - 544; const int tap = v2/16, cl = v2%16; wv = w7[(c0 + cl)*49 + tap]; }
    wl[u] = wv;
  }
  const float* bb = base2 + (size_t)cb*16384*16;
  for (int u = tid; u < 2880; u += 512){
    const int r = u / 288;
    const int rem = u % 288;
    const int xig = rem >> 2;
    const int cq = rem & 3;
    const int y = y0 + r - 3;
    const int xg = x0 + xig - 3;
    f32x4 v = {0.f,0.f,0.f,0.f};
    if ((unsigned)y < 128u && (unsigned)xg < 128u)
      v = *(const f32x4*)(bb + (size_t)(y*128 + xg)*16 + cq*4);
    *(f32x4*)(&tile[(r*72 + xig)*16 + cq*4]) = v;
  }
  __syncthreads();

  const int cq = tid & 3;
  const int xl = (tid >> 2) & 63;
  const int rh = tid >> 8;          // 0..1: row-pair selector
  const float* w3t = wl;
  const float* w5t = wl + 144;
  const float* w7t = wl + 544;

  f32x4 a3[2], a5[2], a7[2];
  #pragma unroll
  for (int r = 0; r < 2; ++r){
    a3[r] = (f32x4){0.f,0.f,0.f,0.f};
    a5[r] = (f32x4){0.f,0.f,0.f,0.f};
    a7[r] = (f32x4){0.f,0.f,0.f,0.f};
  }
  #pragma unroll
  for (int dy = 0; dy < 7; ++dy){
    #pragma unroll
    for (int dx = 0; dx < 7; ++dx){
      const f32x4 w7v = *(const f32x4*)(&w7t[(dy*7 + dx)*16 + cq*4]);
      const bool in5 = (dy >= 1 && dy <= 5 && dx >= 1 && dx <= 5);
      const bool in3 = (dy >= 2 && dy <= 4 && dx >= 2 && dx <= 4);
      f32x4 w5v = {0.f,0.f,0.f,0.f}, w3v = {0.f,0.f,0.f,0.f};
      if (in5) w5v = *(const f32x4*)(&w5t[((dy - 1)*5 + (dx - 1))*16 + cq*4]);
      if (in3) w3v = *(const f32x4*)(&w3t[((dy - 2)*3 + (dx - 2))*16 + cq*4]);
      #pragma unroll
      for (int r = 0; r < 2; ++r){
        const f32x4 f = *(const f32x4*)(&tile[((rh*2 + r + dy)*72 + (xl + dx))*16 + cq*4]);
        a7[r] += f*w7v;
        if (in5) a5[r] += f*w5v;
        if (in3) a3[r] += f*w3v;
      }
    }
  }

  #pragma unroll
  for (int r = 0; r < 2; ++r){
    const int p = (y0 + rh*2 + r)*128 + x0 + xl;
    unsigned short* ob = dwT2 + (size_t)(p - start_px)*3456 + cb*48 + cq*4;
    s16x4 h3, h5, h7;
    #pragma unroll
    for (int j = 0; j < 4; ++j){
      h3[j] = (short)f2h(a3[r][j]);
      h5[j] = (short)f2h(a5[r][j]);
      h7[j] = (short)f2h(a7[r][j]);
    }
    *(s16x4*)(ob)      = h3;
    *(s16x4*)(ob + 16) = h5;
    *(s16x4*)(ob + 32) = h7;
  }
}

// ---- attention partials v2: one block = 64-px slot, ALL 8 heads -------------
// stages 16px x 768 f32 once; qkT read exactly once. part [8][256][2400]
__global__ __launch_bounds__(256, 2)
void k_attn_partial2(const float* __restrict__ qkT, float* __restrict__ part, int slotBase){
  __shared__ float qk[16*772];    // 49.4 KB, padded rows
  const int tid = threadIdx.x;
  const int slot = blockIdx.x;
  const int c0 = tid & 15;
  const int d0 = tid >> 4;

  float acc[8][3][3];
  #pragma unroll
  for (int h = 0; h < 8; ++h)
    #pragma unroll
    for (int i = 0; i < 3; ++i)
      #pragma unroll
      for (int j = 0; j < 3; ++j)
        acc[h][i][j] = 0.f;
  float ssq0 = 0.f, ssq1 = 0.f, ssq2 = 0.f;
  const int ch = tid*3;

  for (int sub = 0; sub < 4; ++sub){
    __syncthreads();
    const int pb = slot*64 + sub*16;
    #pragma unroll
    for (int it = 0; it < 12; ++it){
      const int idx = tid + it*256;
      const int px = idx / 192, s = idx % 192;
      *(f32x4*)(&qk[px*772 + s*4]) = *(const f32x4*)(qkT + (size_t)(pb + px)*768 + s*4);
    }
    __syncthreads();
    for (int px = 0; px < 16; ++px){
      const float* row = &qk[px*772];
      #pragma unroll
      for (int h = 0; h < 8; ++h){
        const float q0 = row[h*48 + c0*3 + 0];
        const float q1 = row[h*48 + c0*3 + 1];
        const float q2 = row[h*48 + c0*3 + 2];
        const float k0 = row[384 + h*48 + d0*3 + 0];
        const float k1 = row[384 + h*48 + d0*3 + 1];
        const float k2 = row[384 + h*48 + d0*3 + 2];
        acc[h][0][0] += q0*k0; acc[h][0][1] += q0*k1; acc[h][0][2] += q0*k2;
        acc[h][1][0] += q1*k0; acc[h][1][1] += q1*k1; acc[h][1][2] += q1*k2;
        acc[h][2][0] += q2*k0; acc[h][2][1] += q2*k1; acc[h][2][2] += q2*k2;
      }
      ssq0 += row[ch]*row[ch];
      ssq1 += row[ch + 1]*row[ch + 1];
      ssq2 += row[ch + 2]*row[ch + 2];
    }
  }

  #pragma unroll
  for (int h = 0; h < 8; ++h){
    float* pp = part + ((size_t)h*256 + slotBase + slot)*2400;
    #pragma unroll
    for (int i = 0; i < 3; ++i)
      #pragma unroll
      for (int j = 0; j < 3; ++j)
        pp[(c0*3 + i)*48 + d0*3 + j] = acc[h][i][j];
  }
  {
    const int hh = (ch < 384) ? (ch / 48) : ((ch - 384) / 48);
    const int cc = (ch < 384) ? (ch % 48) : (48 + ((ch - 384) % 48));
    float* pp = part + ((size_t)hh*256 + slotBase + slot)*2400 + 2304 + cc;
    pp[0] = ssq0; pp[1] = ssq1; pp[2] = ssq2;
  }
}

// ------- reduce 256 partials, l2-norm, temperature, fused 3x topk-softmax ----
__global__ __launch_bounds__(256)
void k_attn_combine(const float* __restrict__ part, const float* __restrict__ temp,
                    const float* __restrict__ scales, float* __restrict__ Acomb){
  __shared__ float att[288];
  const int tid = threadIdx.x;
  const int rg = blockIdx.x;
  const int h = blockIdx.y;
  const int r0 = rg*4;
  for (int u = tid; u < 288; u += 256){
    const int off = (u < 192) ? ((r0 + u/48)*48 + (u % 48)) : (2304 + (u - 192));
    float s = 0.f;
    const float* pb = part + (size_t)h*256*2400 + off;
    for (int c2 = 0; c2 < 256; ++c2) s += pb[c2*2400];
    att[u] = s;
  }
  __syncthreads();
  const int w = tid >> 6;
  const int lane = tid & 63;
  const int c = r0 + w;
  const int d = lane;
  const float tmp = temp[h];
  float v;
  if (d < 48){
    const float nq = fmaxf(sqrtf(att[192 + c]), 1e-12f);
    const float nk = fmaxf(sqrtf(att[240 + d]), 1e-12f);
    v = att[w*48 + d] / (nq*nk) * tmp;
  } else v = -3.0e38f;
  float m = v;
  #pragma unroll
  for (int s = 32; s; s >>= 1) m = fmaxf(m, __shfl_xor(m, s, 64));
  int rk = 0;
  for (int l = 0; l < 48; ++l){
    const float vl = __shfl(v, l, 64);
    rk += ((vl > v) || (vl == v && l < d)) ? 1 : 0;
  }
  const float e = (d < 48) ? expf(v - m) : 0.f;
  float e0 = (rk < 24) ? e : 0.f;
  float e1 = (rk < 32) ? e : 0.f;
  float e2 = (rk < 36) ? e : 0.f;
  #pragma unroll
  for (int s = 32; s; s >>= 1){
    e0 += __shfl_xor(e0, s, 64);
    e1 += __shfl_xor(e1, s, 64);
    e2 += __shfl_xor(e2, s, 64);
  }
  const float wgt = e*(((rk < 24) ? scales[0]/e0 : 0.f)
                     + ((rk < 32) ? scales[1]/e1 : 0.f)
                     + ((rk < 36) ? scales[2]/e2 : 0.f));
  if (d < 48) Acomb[((size_t)h*48 + c)*48 + d] = wgt;
}

// ------------- out[p][h*48+c] = sum_d Acomb[h][c][d] * v[p][d]  (bf16 out) ---
__global__ __launch_bounds__(256, 2)
void k_av(const unsigned short* __restrict__ vT, const float* __restrict__ Acomb,
          unsigned short* __restrict__ outT){
  __shared__ float As[48*49];
  __shared__ float vs[64*48];
  const int tid = threadIdx.x;
  const int pc = blockIdx.x;
  const int h = blockIdx.y;
  for (int u = tid; u < 2304; u += 256)
    As[(u/48)*49 + (u%48)] = Acomb[(size_t)h*2304 + u];
  const int q = tid & 3;
  const int pl = tid >> 2;
  for (int st = 0; st < 4; ++st){
    __syncthreads();
    const int pb = pc*256 + st*64;
    #pragma unroll
    for (int it = 0; it < 2; ++it){
      const int u = tid + it*256;
      if (u < 384){
        const int p = u / 6, sg = u % 6;
        const s16x8 v8 = *(const s16x8*)(vT + (size_t)(pb + p)*384 + h*48 + sg*8);
        float* d = &vs[p*48 + sg*8];
        #pragma unroll
        for (int j = 0; j < 8; ++j) d[j] = bf2f((unsigned short)v8[j]);
      }
    }
    __syncthreads();
    float a[12];
    #pragma unroll
    for (int i = 0; i < 12; ++i) a[i] = 0.f;
    for (int d = 0; d < 48; ++d){
      const float vv = vs[pl*48 + d];
      #pragma unroll
      for (int i = 0; i < 12; ++i) a[i] += As[(q*12 + i)*49 + d]*vv;
    }
    unsigned short* ob = outT + (size_t)(pb + pl)*384 + h*48 + q*12;
    #pragma unroll
    for (int g = 0; g < 3; ++g){
      s16x4 o;
      #pragma unroll
      for (int j = 0; j < 4; ++j) o[j] = (short)f2bf(a[g*4 + j]);
      *(s16x4*)(ob + g*4) = o;
    }
  }
}

// ------------- weight prep ----------------------------------------------------
__global__ __launch_bounds__(256)
void k_f32_to_bf16(const float* __restrict__ in, unsigned short* __restrict__ out, int n4){
  const int i = blockIdx.x*256 + threadIdx.x;
  if (i < n4){
    const f32x4 v = *(const f32x4*)(in + (size_t)i*4);
    s16x4 o;
    #pragma unroll
    for (int j = 0; j < 4; ++j) o[j] = (short)f2bf(v[j]);
    *(s16x4*)(out + (size_t)i*4) = o;
  }
}
__global__ __launch_bounds__(256)
void k_prep_wqkv(const float* __restrict__ w, unsigned short* __restrict__ A){
  const int i = blockIdx.x*256 + threadIdx.x;
  const int o = i / 384, c = i % 384;
  const float v = w[i];
  const unsigned short hi = f2bf(v);
  const unsigned short lo = f2bf(v - bf2f(hi));
  unsigned short* r = A + (size_t)o*1152;
  r[c] = hi; r[384 + c] = hi; r[768 + c] = lo;
}
// pconv weights -> single fp16 plane, K-permuted (k' = cbl*48 + br*16 + cl)
__global__ __launch_bounds__(256)
void k_prep_wp16(const float* __restrict__ w, unsigned short* __restrict__ wp16){
  const int i = blockIdx.x*256 + threadIdx.x;   // 1152*3456 threads
  const int o = i / 3456, k3 = i % 3456;
  const int cbl = k3 / 48, r2 = k3 % 48, br = r2 / 16, cl = r2 % 16;
  wp16[(size_t)o*3456 + k3] = f2h(w[(size_t)o*3456 + br*1152 + cbl*16 + cl]);
}

extern "C" void kernel_launch(void* const* d_in, const int* in_sizes, int n_in,
                              void* d_out, int out_size, void* d_ws, size_t ws_size,
                              hipStream_t stream){
  const float* x         = (const float*)d_in[0];
  const float* w_qkv     = (const float*)d_in[1];
  const float* w_dw3     = (const float*)d_in[2];
  const float* w_dw5     = (const float*)d_in[3];
  const float* w_dw7     = (const float*)d_in[4];
  const float* w_pconv   = (const float*)d_in[5];
  const float* w_proj    = (const float*)d_in[6];
  const float* temperature = (const float*)d_in[7];
  const float* attn_scales = (const float*)d_in[8];
  float* out = (float*)d_out;
  char* ws = (char*)d_ws;
  const size_t MiB = (size_t)1 << 20;

  // fixed region (0..24 MiB)
  unsigned short* Aqkv  = (unsigned short*)(ws);               // 2.53 MiB
  unsigned short* Wp16  = (unsigned short*)(ws + 3*MiB);       // 7.6 MiB
  unsigned short* Wproj = (unsigned short*)(ws + 11*MiB);      // 0.28 MiB
  unsigned short* vT    = (unsigned short*)(ws + 12*MiB);      // 12 MiB
  // tail (last 33 MiB): part [8][256][2400] f32 (18.75) + Acomb + outT (12)
  char* tailp = ws + (ws_size - 33*MiB);
  float*          part  = (float*)tailp;
  float*          Acomb = (float*)(tailp + 20*MiB);
  unsigned short* outT  = (unsigned short*)(tailp + 21*MiB);

  float*          base2;
  float*          qkTc;
  unsigned short* dwT2;
  unsigned short* xT2;
  int units;
  if (ws_size >= 237*MiB){
    // SINGLE-CHUNK: base2@24 (dead after dwconv) aliased by qkTc; dwT2@96 (108 MiB)
    base2 = (float*)(ws + 24*MiB);
    qkTc  = (float*)(ws + 24*MiB);             // aliases base2 (base2 dead when f9 runs)
    dwT2  = (unsigned short*)(ws + 96*MiB);    // [16384][3456] fp16 = 108 MiB
    xT2   = (unsigned short*)(ws + 96*MiB);    // aliases dwT2 (dead before dwconv)
    units = 16;
  } else {
    // CHUNKED fallback: base2@24..96, qkTc@96, dwT2 after
    base2 = (float*)(ws + 24*MiB);
    long long avail = (long long)ws_size - (long long)(96 + 33)*MiB;
    units = (int)(avail / (1024LL*768*4 + 1024LL*3456*2));
    if (units > 16) units = 16;
    units &= ~1;
    if (units < 2) units = 2;
    qkTc = (float*)(ws + 96*MiB);
    dwT2 = (unsigned short*)(ws + 96*MiB + (size_t)units*3*MiB);
    xT2  = (unsigned short*)(ws + 96*MiB);
  }

  k_prep_wqkv<<<dim3(1728), dim3(256), 0, stream>>>(w_qkv, Aqkv);
  k_prep_wp16<<<dim3(15552), dim3(256), 0, stream>>>(w_pconv, Wp16);
  k_f32_to_bf16<<<dim3(144), dim3(256), 0, stream>>>(w_proj, Wproj, 36864);

  for (int b = 0; b < 2; ++b){
    const float* xb = x + (size_t)b*384*16384;
    float* outb = out + (size_t)b*384*16384;
    k_transpose_xhl<<<dim3(256, 6), dim3(256), 0, stream>>>(xb, xT2);
    // base = Wqkv * x  (3-term hi/lo, blocked f32 out); 96x256 tile, 768 blocks
    k_gemm4w<<<dim3(768), dim3(256), 0, stream>>>(Aqkv, xT2, base2);
    for (int u0 = 0; u0 < 16; u0 += units){
      const int cu = (units < 16 - u0) ? units : (16 - u0);
      const int start = u0*1024, cpx = cu*1024;
      k_dwconv<<<dim3(72, cu*2, 2), dim3(512), 0, stream>>>(base2, w_dw3, w_dw5, w_dw7,
                                                            dwT2, start/128, start, cpx);
      // qkv in one fp16 GEMM (96x256 tile, 12*(cpx/256) blocks), px-major B rows
      k_gemm_f9<<<dim3((cpx/256)*12), dim3(256), 0, stream>>>(Wp16, dwT2, qkTc, vT, start, cpx);
      // partial QK^T dots: one block per 64-px slot, all 8 heads, single read
      k_attn_partial2<<<dim3(cpx/64), dim3(256), 0, stream>>>(qkTc, part, start/64);
    }
    k_attn_combine<<<dim3(12, 8), dim3(256), 0, stream>>>(part, temperature, attn_scales, Acomb);
    k_av<<<dim3(64, 8), dim3(256), 0, stream>>>(vT, Acomb, outT);
    // proj: 96x128 tile, 512 blocks = exactly 2/CU, direct f32 write
    k_gemm_proj<<<dim3(512), dim3(256), 0, stream>>>(Wproj, outT, outb);
  }
  (void)in_sizes; (void)n_in; (void)out_size; (void)ws_size;
}